// Round 4
// baseline (54.709 us; speedup 1.0000x reference)
//
#include <hip/hip_runtime.h>
#include <hip/hip_bf16.h>

#define B_DIM 128
#define C_DIM 128
#define T_DIM 777
#define T_PAD 832   // 26 * 32
#define P_DIM 500
#define P_PAD 512
#define NCLS  5
#define EPSV  1e-4f
#define NTILE 26    // T_PAD / 32

typedef unsigned short u16;
typedef unsigned int   u32;
typedef __attribute__((ext_vector_type(8))) short short8;   // 8 bf16 = 4 VGPR
typedef __attribute__((ext_vector_type(4))) float f32x4;

__device__ __forceinline__ u16 f2bf(float f) {
    u32 u = __float_as_uint(f);
    u += 0x7FFFu + ((u >> 16) & 1u);     // RNE
    return (u16)(u >> 16);
}

__device__ __forceinline__ u32 cvt_pk_bf16(float a, float b) {
    u32 r;
    asm("v_cvt_pk_bf16_f32 %0, %1, %2" : "=v"(r) : "v"(a), "v"(b));
    return r;
}

// ---------------- kernel 1: x fp32 -> xbf[b][t 0..831][c 0..127] bf16 + x2[b][t] fp32 ----------
// (r1's verified prep: coalesced t-contiguous reads, LDS transpose, linear granule store)
__global__ __launch_bounds__(256) void prep_x(const float* __restrict__ x,
                                              u16* __restrict__ xbf,
                                              float* __restrict__ x2) {
    const int tc = blockIdx.x;           // 0..12 (64 t's each)
    const int b  = blockIdx.y;
    const int tid = threadIdx.x, w = tid >> 6, l = tid & 63;
    __shared__ __align__(16) u16 xt[64][136];  // +8 pad
    const int t_loc = w * 16 + (l & 15);
    const int cg = l >> 4;                     // 0..3
    const int t = tc * 64 + t_loc;
    const float* xb = x + (size_t)b * C_DIM * T_DIM;
    float acc = 0.f;
#pragma unroll 8
    for (int c0 = 0; c0 < C_DIM; c0 += 4) {
        int c = c0 + cg;
        float v = (t < T_DIM) ? xb[c * T_DIM + t] : 0.f;
        acc = fmaf(v, v, acc);
        xt[t_loc][c] = f2bf(v);
    }
    acc += __shfl_xor(acc, 16);
    acc += __shfl_xor(acc, 32);
    if (cg == 0) x2[b * T_PAD + t] = (t < T_DIM) ? acc : 1e30f;
    __syncthreads();
    int4* dst = (int4*)(xbf + ((size_t)b * T_PAD + tc * 64) * C_DIM);
#pragma unroll
    for (int q = 0; q < 4; ++q) {
        int f = q * 256 + tid;                 // 1024 16B-granules
        int tr = f >> 4, g = f & 15;
        dst[f] = *(const int4*)((const char*)xt + tr * 272 + g * 16);
    }
}

// ---------------- kernel 2: pure staging-loop MFMA GEMM + min over t ----------------
// grid 768 = b(128) x pt(2) x th(3); block 256 (4 waves); wave owns 64 protos.
// Per iter: 2 preloaded int4 -> swizzled ds_write_b128 -> bar -> 8 ds_read_b128 + 32 MFMA + fold.
// wsmin[th][b][p] = min over th's t-range of (x2[t] - 2*x.p)
__global__ __launch_bounds__(256, 3) void gemm_min(
    const int4* __restrict__ xg,       // xbf as 16B granules: [b][832 t][16 gc]
    const float* __restrict__ x2,
    const float* __restrict__ proto,
    float* __restrict__ wsmin) {

    const int o   = blockIdx.x;               // XCD-bijective: 768 = 8 XCD x 96
    const int xcd = o & 7, j = o >> 3;        // j: 0..95
    const int bl  = j / 6;                    // 0..15
    const int r6  = j - bl * 6;               // 0..5
    const int b   = xcd * 16 + bl;
    const int pt  = r6 & 1;
    const int th  = r6 >> 1;                  // 0..2
    const int it0 = (th == 0) ? 0 : (th == 1 ? 9 : 17);
    const int itN = (th == 0) ? 9 : (th == 1 ? 17 : NTILE);

    const int tid = threadIdx.x;
    const int w = tid >> 6, l = tid & 63;
    const int row16 = l & 15, kq = l >> 4;    // kq: 0..3
    const int wp = pt * 256 + w * 64;         // wave's proto base (64 rows)

    __shared__ __align__(16) char smem[32 * 256];   // 32 t x 128 c bf16, XOR-swizzled granules

    // ---- prologue: prototype A-frags in registers (bf16 via cvt_pk) ----
    short8 afr[4][4];
#pragma unroll
    for (int ps = 0; ps < 4; ++ps) {
        const int r = wp + ps * 16 + row16;
#pragma unroll
        for (int kst = 0; kst < 4; ++kst) {
            const int k0 = kst * 32 + kq * 8;
            union { short8 s; u32 d[4]; } t;
            if (r < P_DIM) {
                float4 u0 = *(const float4*)(proto + r * C_DIM + k0);
                float4 u1 = *(const float4*)(proto + r * C_DIM + k0 + 4);
                t.d[0] = cvt_pk_bf16(u0.x, u0.y);
                t.d[1] = cvt_pk_bf16(u0.z, u0.w);
                t.d[2] = cvt_pk_bf16(u1.x, u1.y);
                t.d[3] = cvt_pk_bf16(u1.z, u1.w);
            } else {
                t.d[0] = t.d[1] = t.d[2] = t.d[3] = 0u;
            }
            afr[ps][kst] = t.s;
        }
    }

    // staging coords: thread stages granules tid and tid+256 of each 512-granule tile
    // LDS dest: granule i -> (i>>4)*256 + (((i&15) ^ ((i>>4)&7))<<4); d1 = d0 + 4096
    const int d0 = (tid >> 4) * 256 + ((((tid & 15) ^ ((tid >> 4) & 7))) << 4);
    const int d1 = d0 + 4096;
    const int4* gb = xg + (size_t)b * T_PAD * 16;   // granules for batch b
    const float* x2b = x2 + b * T_PAD;

    f32x4 minv[4];
#pragma unroll
    for (int ps = 0; ps < 4; ++ps) minv[ps] = (f32x4){1e30f, 1e30f, 1e30f, 1e30f};

    // one-deep preload
    int4 v0 = gb[it0 * 512 + tid];
    int4 v1 = gb[it0 * 512 + 256 + tid];
    float xa = x2b[it0 * 32 + row16];
    float xc = x2b[it0 * 32 + 16 + row16];

    for (int it = it0; it < itN; ++it) {
        __syncthreads();                       // previous compute done reading LDS
        *(int4*)(smem + d0) = v0;
        *(int4*)(smem + d1) = v1;
        __syncthreads();                       // tile visible

        const float cxa = xa, cxc = xc;
        if (it + 1 < itN) {                    // preload next tile; latency hides under MFMA
            v0 = gb[(it + 1) * 512 + tid];
            v1 = gb[(it + 1) * 512 + 256 + tid];
            xa = x2b[(it + 1) * 32 + row16];
            xc = x2b[(it + 1) * 32 + 16 + row16];
        }

        f32x4 acc[4][2];
#pragma unroll
        for (int ps = 0; ps < 4; ++ps)
#pragma unroll
            for (int ts = 0; ts < 2; ++ts) acc[ps][ts] = (f32x4){0.f, 0.f, 0.f, 0.f};

        __builtin_amdgcn_s_setprio(1);
#pragma unroll
        for (int kst = 0; kst < 4; ++kst) {
            short8 bfr[2];
#pragma unroll
            for (int ts = 0; ts < 2; ++ts) {
                const int tl = ts * 16 + row16;
                const int gr = (kst * 4 + kq) ^ (tl & 7);
                bfr[ts] = *(const short8*)(smem + tl * 256 + (gr << 4));
            }
#pragma unroll
            for (int ps = 0; ps < 4; ++ps)
#pragma unroll
                for (int ts = 0; ts < 2; ++ts)
                    acc[ps][ts] = __builtin_amdgcn_mfma_f32_16x16x32_bf16(
                        afr[ps][kst], bfr[ts], acc[ps][ts], 0, 0, 0);
        }
        __builtin_amdgcn_s_setprio(0);

#pragma unroll
        for (int ps = 0; ps < 4; ++ps)
#pragma unroll
            for (int q = 0; q < 4; ++q) {
                minv[ps][q] = fminf(minv[ps][q], fmaf(-2.f, acc[ps][0][q], cxa));
                minv[ps][q] = fminf(minv[ps][q], fmaf(-2.f, acc[ps][1][q], cxc));
            }
    }

    // min across the 16 t-columns (lane bits 0..3)
#pragma unroll
    for (int m = 1; m <= 8; m <<= 1)
#pragma unroll
        for (int ps = 0; ps < 4; ++ps)
#pragma unroll
            for (int q = 0; q < 4; ++q)
                minv[ps][q] = fminf(minv[ps][q], __shfl_xor(minv[ps][q], m));

    if (row16 == 0) {
#pragma unroll
        for (int ps = 0; ps < 4; ++ps) {
            const int p = wp + ps * 16 + kq * 4;   // C/D: row = kq*4+q
            *(float4*)(&wsmin[((size_t)th * B_DIM + b) * P_PAD + p]) =
                make_float4(minv[ps][0], minv[ps][1], minv[ps][2], minv[ps][3]);
        }
    }
}

// ---------------- kernel 3: p2 + 3-way min-merge + clamp + log-sim + @W ----------------
__global__ __launch_bounds__(256) void combine_logits(
    const float* __restrict__ proto, const float* __restrict__ lw,
    const float* __restrict__ wsmin, float* __restrict__ out) {
    const int b = blockIdx.x, tid = threadIdx.x;
    float a[NCLS] = {0.f, 0.f, 0.f, 0.f, 0.f};
    for (int p = tid; p < P_DIM; p += 256) {
        const float4* pr = (const float4*)(proto + p * C_DIM);
        float p2 = 0.f;
#pragma unroll
        for (int i = 0; i < 32; ++i) {
            float4 u = pr[i];
            p2 += u.x*u.x + u.y*u.y + u.z*u.z + u.w*u.w;
        }
        const float m0 = wsmin[(0 * B_DIM + b) * P_PAD + p];
        const float m1 = wsmin[(1 * B_DIM + b) * P_PAD + p];
        const float m2 = wsmin[(2 * B_DIM + b) * P_PAD + p];
        const float m  = fminf(fminf(m0, m1), m2);
        const float md = fmaxf(m + p2, 0.f);
        const float sim = logf((md + 1.f) / (md + EPSV));
#pragma unroll
        for (int n = 0; n < NCLS; ++n) a[n] = fmaf(sim, lw[p * NCLS + n], a[n]);
    }
#pragma unroll
    for (int m = 1; m <= 32; m <<= 1)
#pragma unroll
        for (int n = 0; n < NCLS; ++n) a[n] += __shfl_xor(a[n], m);
    __shared__ float red[4][NCLS];
    const int w = tid >> 6, l = tid & 63;
    if (l == 0) {
#pragma unroll
        for (int n = 0; n < NCLS; ++n) red[w][n] = a[n];
    }
    __syncthreads();
    if (tid < NCLS)
        out[b * NCLS + tid] = red[0][tid] + red[1][tid] + red[2][tid] + red[3][tid];
}

// ---------------- fallback (no workspace): slow but correct ----------------
__global__ __launch_bounds__(256) void fallback_k(const float* __restrict__ x,
                                                  const float* __restrict__ proto,
                                                  const float* __restrict__ lw,
                                                  float* __restrict__ out) {
    __shared__ float x2s[T_DIM];
    __shared__ float sims[P_DIM];
    int b = blockIdx.x, tid = threadIdx.x;
    for (int t = tid; t < T_DIM; t += 256) {
        float a = 0.f;
        for (int c = 0; c < C_DIM; ++c) { float v = x[((size_t)b * C_DIM + c) * T_DIM + t]; a = fmaf(v, v, a); }
        x2s[t] = a;
    }
    __syncthreads();
    for (int p = tid; p < P_DIM; p += 256) {
        float p2 = 0.f;
        for (int c = 0; c < C_DIM; ++c) { float v = proto[p * C_DIM + c]; p2 = fmaf(v, v, p2); }
        float mind = 1e30f;
        for (int t = 0; t < T_DIM; ++t) {
            float xp = 0.f;
            for (int c = 0; c < C_DIM; ++c)
                xp = fmaf(x[((size_t)b * C_DIM + c) * T_DIM + t], proto[p * C_DIM + c], xp);
            float d = fmaxf(x2s[t] - 2.f * xp + p2, 0.f);
            mind = fminf(mind, d);
        }
        sims[p] = logf((mind + 1.f) / (mind + EPSV));
    }
    __syncthreads();
    if (tid < NCLS) {
        float a = 0.f;
        for (int p = 0; p < P_DIM; ++p) a = fmaf(sims[p], lw[p * NCLS + tid], a);
        out[b * NCLS + tid] = a;
    }
}

extern "C" void kernel_launch(void* const* d_in, const int* in_sizes, int n_in,
                              void* d_out, int out_size, void* d_ws, size_t ws_size,
                              hipStream_t stream) {
    const float* x     = (const float*)d_in[0];
    const float* proto = (const float*)d_in[1];
    const float* lw    = (const float*)d_in[2];
    float* out = (float*)d_out;

    const size_t xbf_bytes = (size_t)B_DIM * T_PAD * C_DIM * 2;      // 27,262,976
    const size_t x2_off  = xbf_bytes;
    const size_t min_off = x2_off + (size_t)B_DIM * T_PAD * 4;
    const size_t need    = min_off + (size_t)3 * B_DIM * P_PAD * 4;  // ~28.5 MB

    if (ws_size >= need) {
        u16*   xbf   = (u16*)d_ws;
        float* x2    = (float*)((char*)d_ws + x2_off);
        float* wsmin = (float*)((char*)d_ws + min_off);
        prep_x        <<<dim3(T_PAD / 64, B_DIM), 256, 0, stream>>>(x, xbf, x2);
        gemm_min      <<<dim3(768),               256, 0, stream>>>((const int4*)xbf, x2, proto, wsmin);
        combine_logits<<<dim3(B_DIM),             256, 0, stream>>>(proto, lw, wsmin, out);
    } else {
        fallback_k<<<dim3(B_DIM), 256, 0, stream>>>(x, proto, lw, out);
    }
}

// Round 5
// 48.757 us; speedup vs baseline: 1.1221x; 1.1221x over previous
//
#include <hip/hip_runtime.h>
#include <hip/hip_bf16.h>

#define B_DIM 128
#define C_DIM 128
#define T_DIM 777
#define P_DIM 500
#define P_PAD 512
#define NCLS  5
#define EPSV  1e-4f
#define NTILE 13      // ceil(777/64)
#define SPLIT 7       // th0: tiles 0..6 (t<448), th1: tiles 7..12

typedef unsigned short u16;
typedef unsigned int   u32;
typedef __attribute__((ext_vector_type(8))) short short8;   // 8 bf16 = 4 VGPR
typedef __attribute__((ext_vector_type(4))) float f32x4;
typedef float float4u __attribute__((ext_vector_type(4), aligned(4)));  // stride 777 is odd -> 4B align

__device__ __forceinline__ u32 cvt_pk_bf16(float a, float b) {
    u32 r;
    asm("v_cvt_pk_bf16_f32 %0, %1, %2" : "=v"(r) : "v"(a), "v"(b));
    return r;
}

// ---------------- fused: x2 prepass -> [64t x 128c] bf16 LDS tiles -> MFMA -> min over t -------
// grid 512 = b(128) x pt(2) x th(2); block 256 (4 waves); wave owns 64 protos (A in regs).
// wsmin[th][b][p] = min over th's t-range of (x2[t] - 2*x.p)   (p2/clamp/log deferred)
__global__ __launch_bounds__(256, 2) void fused_gemm_min(
    const float* __restrict__ x,
    const float* __restrict__ proto,
    float* __restrict__ wsmin) {

    const int o   = blockIdx.x;               // XCD-bijective: 512 = 8 XCD x 64
    const int xcd = o & 7, j = o >> 3;        // j: 0..63
    const int b   = xcd * 16 + (j >> 2);
    const int pt  = (j >> 1) & 1, th = j & 1;
    const int it0 = th ? SPLIT : 0;
    const int itN = th ? NTILE : SPLIT;
    const int tb0 = it0 * 64;
    const int nT  = (itN - it0) * 64;         // 448 or 384

    const int tid = threadIdx.x;
    const int w = tid >> 6, l = tid & 63;
    const int row16 = l & 15, kq = l >> 4;    // kq: 0..3
    const int wp = pt * 256 + w * 64;         // wave's proto base (64 rows)

    // loader: thread owns 4 c-rows x (4t in each of 2 halves); block covers 128c x 64t
    const int c0  = (tid >> 3) << 2;          // 0..124
    const int tl0 = (tid & 7) << 2;           // 0..28

    __shared__ __align__(16) char  smem[64 * 256];   // 64 t-rows x 128 c bf16, 16B-granule XOR swizzle
    __shared__ __align__(16) float x2s[448];         // block's own t-range

    const float* xb = x + (size_t)b * C_DIM * T_DIM;

    // ---- x2 prepass: coalesced (lane==t) re-read of this block's x slice; warms L2 ----
    for (int i = tid; i < nT; i += 256) {
        const int t = tb0 + i;
        float a = 0.f;
        if (t < T_DIM) {
#pragma unroll 8
            for (int c = 0; c < C_DIM; ++c) {
                const float v = xb[c * T_DIM + t];
                a = fmaf(v, v, a);
            }
            x2s[i] = a;
        } else {
            x2s[i] = 1e30f;                    // padded t never wins the min
        }
    }

    // ---- prototype A-frags in registers (bf16 via cvt_pk) ----
    short8 afr[4][4];
#pragma unroll
    for (int ps = 0; ps < 4; ++ps) {
        const int r = wp + ps * 16 + row16;
#pragma unroll
        for (int kst = 0; kst < 4; ++kst) {
            const int k0 = kst * 32 + kq * 8;
            union { short8 s; u32 d[4]; } t;
            if (r < P_DIM) {
                float4 u0 = *(const float4*)(proto + r * C_DIM + k0);
                float4 u1 = *(const float4*)(proto + r * C_DIM + k0 + 4);
                t.d[0] = cvt_pk_bf16(u0.x, u0.y);
                t.d[1] = cvt_pk_bf16(u0.z, u0.w);
                t.d[2] = cvt_pk_bf16(u1.x, u1.y);
                t.d[3] = cvt_pk_bf16(u1.z, u1.w);
            } else {
                t.d[0] = t.d[1] = t.d[2] = t.d[3] = 0u;
            }
            afr[ps][kst] = t.s;
        }
    }

    float vb[2][4][4];   // [t-half][c-row][t-col], compile-time indexed (rule #20)
    auto loadv = [&](int it) {
#pragma unroll
        for (int h = 0; h < 2; ++h) {
            const int tb = it * 64 + h * 32 + tl0;
            if (tb + 3 < T_DIM) {
#pragma unroll
                for (int r = 0; r < 4; ++r) {
                    float4u u = *(const float4u*)(xb + (c0 + r) * T_DIM + tb);
                    vb[h][r][0]=u[0]; vb[h][r][1]=u[1]; vb[h][r][2]=u[2]; vb[h][r][3]=u[3];
                }
            } else {
#pragma unroll
                for (int r = 0; r < 4; ++r)
#pragma unroll
                    for (int jj = 0; jj < 4; ++jj) {
                        const int t = (tb + jj < T_DIM) ? (tb + jj) : (T_DIM - 1);  // clamp; x2 kills it
                        vb[h][r][jj] = xb[(c0 + r) * T_DIM + t];
                    }
            }
        }
    };

    f32x4 minv[4];
#pragma unroll
    for (int ps = 0; ps < 4; ++ps) minv[ps] = (f32x4){1e30f, 1e30f, 1e30f, 1e30f};

    __syncthreads();                           // x2s ready
    loadv(it0);                                // L2-hot from prepass

    for (int it = it0; it < itN; ++it) {
        // ---- stage: convert + transposed swizzled write (8 x ds_write_b64) ----
#pragma unroll
        for (int h = 0; h < 2; ++h)
#pragma unroll
            for (int jj = 0; jj < 4; ++jj) {
                const u32 lo = cvt_pk_bf16(vb[h][0][jj], vb[h][1][jj]);
                const u32 hi = cvt_pk_bf16(vb[h][2][jj], vb[h][3][jj]);
                const int tl  = h * 32 + tl0 + jj;
                const int off = tl * 256 + (((c0 >> 3) ^ (tl & 7)) << 4) + ((c0 & 4) << 1);
                *(uint2*)(smem + off) = make_uint2(lo, hi);
            }
        __syncthreads();                       // tile visible

        if (it + 1 < itN) loadv(it + 1);       // vb is dead; refill under the MFMA phase

        // x2 for the 4 t-subtiles of this tile
        float xv[4];
#pragma unroll
        for (int ts = 0; ts < 4; ++ts)
            xv[ts] = x2s[(it - it0) * 64 + ts * 16 + row16];

        f32x4 acc[4][4];
#pragma unroll
        for (int ps = 0; ps < 4; ++ps)
#pragma unroll
            for (int ts = 0; ts < 4; ++ts) acc[ps][ts] = (f32x4){0.f, 0.f, 0.f, 0.f};

        __builtin_amdgcn_s_setprio(1);
#pragma unroll
        for (int kst = 0; kst < 4; ++kst) {
            short8 bfr[4];
#pragma unroll
            for (int ts = 0; ts < 4; ++ts) {
                const int tl = ts * 16 + row16;
                const int gr = (kst * 4 + kq) ^ (tl & 7);
                bfr[ts] = *(const short8*)(smem + tl * 256 + (gr << 4));
            }
#pragma unroll
            for (int ps = 0; ps < 4; ++ps)
#pragma unroll
                for (int ts = 0; ts < 4; ++ts)
                    acc[ps][ts] = __builtin_amdgcn_mfma_f32_16x16x32_bf16(
                        afr[ps][kst], bfr[ts], acc[ps][ts], 0, 0, 0);
        }
        __builtin_amdgcn_s_setprio(0);

#pragma unroll
        for (int ps = 0; ps < 4; ++ps)
#pragma unroll
            for (int ts = 0; ts < 4; ++ts)
#pragma unroll
                for (int q = 0; q < 4; ++q)
                    minv[ps][q] = fminf(minv[ps][q], fmaf(-2.f, acc[ps][ts][q], xv[ts]));

        __syncthreads();                       // done reading smem
    }

    // min across the 16 t-columns (lane bits 0..3)
#pragma unroll
    for (int m = 1; m <= 8; m <<= 1)
#pragma unroll
        for (int ps = 0; ps < 4; ++ps)
#pragma unroll
            for (int q = 0; q < 4; ++q)
                minv[ps][q] = fminf(minv[ps][q], __shfl_xor(minv[ps][q], m));

    if (row16 == 0) {
#pragma unroll
        for (int ps = 0; ps < 4; ++ps) {
            const int p = wp + ps * 16 + kq * 4;   // C/D: row = kq*4+q
            *(float4*)(&wsmin[((size_t)th * B_DIM + b) * P_PAD + p]) =
                make_float4(minv[ps][0], minv[ps][1], minv[ps][2], minv[ps][3]);
        }
    }
}

// ---------------- combine: p2 + 2-way min-merge + clamp + log-sim + @W ----------------
__global__ __launch_bounds__(256) void combine_logits(
    const float* __restrict__ proto, const float* __restrict__ lw,
    const float* __restrict__ wsmin, float* __restrict__ out) {
    const int b = blockIdx.x, tid = threadIdx.x;
    float a[NCLS] = {0.f, 0.f, 0.f, 0.f, 0.f};
    for (int p = tid; p < P_DIM; p += 256) {
        const float4* pr = (const float4*)(proto + p * C_DIM);
        float p2 = 0.f;
#pragma unroll
        for (int i = 0; i < 32; ++i) {
            float4 u = pr[i];
            p2 += u.x*u.x + u.y*u.y + u.z*u.z + u.w*u.w;
        }
        const float m0 = wsmin[(0 * B_DIM + b) * P_PAD + p];
        const float m1 = wsmin[(1 * B_DIM + b) * P_PAD + p];
        const float m  = fminf(m0, m1);
        const float md = fmaxf(m + p2, 0.f);
        const float sim = logf((md + 1.f) / (md + EPSV));
#pragma unroll
        for (int n = 0; n < NCLS; ++n) a[n] = fmaf(sim, lw[p * NCLS + n], a[n]);
    }
#pragma unroll
    for (int m = 1; m <= 32; m <<= 1)
#pragma unroll
        for (int n = 0; n < NCLS; ++n) a[n] += __shfl_xor(a[n], m);
    __shared__ float red[4][NCLS];
    const int w = tid >> 6, l = tid & 63;
    if (l == 0) {
#pragma unroll
        for (int n = 0; n < NCLS; ++n) red[w][n] = a[n];
    }
    __syncthreads();
    if (tid < NCLS)
        out[b * NCLS + tid] = red[0][tid] + red[1][tid] + red[2][tid] + red[3][tid];
}

// ---------------- fallback (no workspace): slow but correct ----------------
__global__ __launch_bounds__(256) void fallback_k(const float* __restrict__ x,
                                                  const float* __restrict__ proto,
                                                  const float* __restrict__ lw,
                                                  float* __restrict__ out) {
    __shared__ float x2s[T_DIM];
    __shared__ float sims[P_DIM];
    int b = blockIdx.x, tid = threadIdx.x;
    for (int t = tid; t < T_DIM; t += 256) {
        float a = 0.f;
        for (int c = 0; c < C_DIM; ++c) { float v = x[((size_t)b * C_DIM + c) * T_DIM + t]; a = fmaf(v, v, a); }
        x2s[t] = a;
    }
    __syncthreads();
    for (int p = tid; p < P_DIM; p += 256) {
        float p2 = 0.f;
        for (int c = 0; c < C_DIM; ++c) { float v = proto[p * C_DIM + c]; p2 = fmaf(v, v, p2); }
        float mind = 1e30f;
        for (int t = 0; t < T_DIM; ++t) {
            float xp = 0.f;
            for (int c = 0; c < C_DIM; ++c)
                xp = fmaf(x[((size_t)b * C_DIM + c) * T_DIM + t], proto[p * C_DIM + c], xp);
            float d = fmaxf(x2s[t] - 2.f * xp + p2, 0.f);
            mind = fminf(mind, d);
        }
        sims[p] = logf((mind + 1.f) / (mind + EPSV));
    }
    __syncthreads();
    if (tid < NCLS) {
        float a = 0.f;
        for (int p = 0; p < P_DIM; ++p) a = fmaf(sims[p], lw[p * NCLS + tid], a);
        out[b * NCLS + tid] = a;
    }
}

extern "C" void kernel_launch(void* const* d_in, const int* in_sizes, int n_in,
                              void* d_out, int out_size, void* d_ws, size_t ws_size,
                              hipStream_t stream) {
    const float* x     = (const float*)d_in[0];
    const float* proto = (const float*)d_in[1];
    const float* lw    = (const float*)d_in[2];
    float* out = (float*)d_out;

    const size_t need = (size_t)2 * B_DIM * P_PAD * sizeof(float);   // 512 KB

    if (ws_size >= need) {
        float* wsmin = (float*)d_ws;
        fused_gemm_min<<<dim3(512), 256, 0, stream>>>(x, proto, wsmin);
        combine_logits<<<dim3(B_DIM), 256, 0, stream>>>(proto, lw, wsmin, out);
    } else {
        fallback_k<<<dim3(B_DIM), 256, 0, stream>>>(x, proto, lw, out);
    }
}